// Round 5
// baseline (664.596 us; speedup 1.0000x reference)
//
#include <hip/hip_runtime.h>
#include <hip/hip_cooperative_groups.h>

namespace cg = cooperative_groups;

#define D   256   // columns
#define D4  64    // columns as float4

typedef float f4 __attribute__((ext_vector_type(4)));

// Fused: phase1 per-block partial col-sumsq -> grid.sync ->
//        phase2 (64 blocks) fold partials in double, write inv ->
//        grid.sync -> phase3 scale own chunk in REVERSE (tail still L2/L3
//        resident from phase1), non-temporal stores.
__global__ __launch_bounds__(256, 8) void fused_colnorm(
    const f4* __restrict__ x4, f4* __restrict__ out4,
    float* __restrict__ part, float* __restrict__ inv,
    int rows, int nb) {
    cg::grid_group grid = cg::this_grid();

    __shared__ union {
        f4     red1[256];
        double red2[4][256];
    } sh;
    __shared__ float sinv[D];

    const int t   = threadIdx.x;
    const int cgi = t & 63;   // float4 column group
    const int ro  = t >> 6;   // row phase 0..3
    const int b   = blockIdx.x;
    const int rows_per_block = rows / nb;          // both powers of two
    const int r0 = b * rows_per_block;
    const int r1 = r0 + rows_per_block;

    // ---- Phase 1: partial column sums of squares (forward stream) ----
    f4 acc = (f4)0.f;
    for (int r = r0 + ro; r < r1; r += 4) {
        f4 v = x4[(size_t)r * D4 + cgi];           // wave reads 1 KiB
        acc += v * v;
    }
    sh.red1[t] = acc;
    __syncthreads();
    if (t < 64) {
        f4 s = sh.red1[t] + sh.red1[t + 64] + sh.red1[t + 128] + sh.red1[t + 192];
        ((f4*)part)[(size_t)b * D4 + t] = s;       // deterministic slot
    }
    grid.sync();

    // ---- Phase 2: fold partials (double), 64 blocks, one f4-group each --
    if (b < 64) {
        const f4* part4 = (const f4*)part;
        double sx = 0.0, sy = 0.0, sz = 0.0, sw = 0.0;
        for (int i = t; i < nb; i += 256) {
            f4 v = part4[(size_t)i * D4 + b];
            sx += (double)v.x; sy += (double)v.y;
            sz += (double)v.z; sw += (double)v.w;
        }
        sh.red2[0][t] = sx; sh.red2[1][t] = sy;
        sh.red2[2][t] = sz; sh.red2[3][t] = sw;
        __syncthreads();
        for (int ofs = 128; ofs > 0; ofs >>= 1) {
            if (t < ofs) {
                sh.red2[0][t] += sh.red2[0][t + ofs];
                sh.red2[1][t] += sh.red2[1][t + ofs];
                sh.red2[2][t] += sh.red2[2][t + ofs];
                sh.red2[3][t] += sh.red2[3][t + ofs];
            }
            __syncthreads();
        }
        if (t < 4) inv[b * 4 + t] = (float)(1.0 / sqrt(sh.red2[t][0]));
    }
    grid.sync();

    // ---- Phase 3: scale own chunk, reverse order, NT stores ----
    if (t < D) sinv[t] = inv[t];
    __syncthreads();
    const f4 s = ((const f4*)sinv)[cgi];
    for (int r = r1 - 4 + ro; r >= r0; r -= 4) {   // rows_per_block % 4 == 0
        const size_t idx = (size_t)r * D4 + cgi;
        f4 v = x4[idx];
        __builtin_nontemporal_store(v * s, &out4[idx]);
    }
}

extern "C" void kernel_launch(void* const* d_in, const int* in_sizes, int n_in,
                              void* d_out, int out_size, void* d_ws, size_t ws_size,
                              hipStream_t stream) {
    const float* x = (const float*)d_in[0];
    float* out = (float*)d_out;
    const size_t n = (size_t)in_sizes[0];          // 524288 * 256
    const int rows = (int)(n / D);

    // Target 2048 blocks (8/CU, full occupancy); clamp to co-resident
    // capacity so the cooperative launch is always valid.
    int blocksPerCU = 0;
    hipOccupancyMaxActiveBlocksPerMultiprocessor(&blocksPerCU, fused_colnorm, 256, 0);
    int numCU = 0;
    hipDeviceGetAttribute(&numCU, hipDeviceAttributeMultiprocessorCount, 0);
    int maxCo = (blocksPerCU > 0 && numCU > 0) ? blocksPerCU * numCU : 2048;

    int nb = 2048;
    while (nb > 64 && (nb > maxCo ||
           ((size_t)nb * D + D) * sizeof(float) > ws_size)) nb >>= 1;

    float* part = (float*)d_ws;
    float* inv  = part + (size_t)nb * D;

    void* args[] = { (void*)&x, (void*)&out, (void*)&part, (void*)&inv,
                     (void*)&rows, (void*)&nb };
    hipLaunchCooperativeKernel((void*)fused_colnorm, dim3(nb), dim3(256),
                               args, 0, stream);
}

// Round 6
// 316.586 us; speedup vs baseline: 2.0993x; 2.0993x over previous
//
#include <hip/hip_runtime.h>

#define D   256   // columns
#define D4  64    // columns as float4

typedef float f4 __attribute__((ext_vector_type(4)));

// Kernel 1: per-block partial column sums of squares.
// Block = 256 threads = 64 column-groups (float4) x 4 row-phases.
__global__ __launch_bounds__(256) void colsq_partial(
    const f4* __restrict__ x4, float* __restrict__ part,
    int rows, int rows_per_block) {
    __shared__ f4 red[256];
    const int t  = threadIdx.x;
    const int cg = t & 63;   // which float4 column group
    const int ro = t >> 6;   // row phase 0..3
    const int r0 = blockIdx.x * rows_per_block;
    const int r1 = min(r0 + rows_per_block, rows);

    f4 acc = (f4)0.f;
    for (int r = r0 + ro; r < r1; r += 4) {
        f4 v = x4[(size_t)r * D4 + cg];   // wave reads 1 KiB contiguous
        acc += v * v;
    }
    red[t] = acc;
    __syncthreads();
    if (t < 64) {
        f4 s = red[t] + red[t + 64] + red[t + 128] + red[t + 192];
        ((f4*)part)[(size_t)blockIdx.x * D4 + t] = s;   // deterministic slot
    }
}

// Kernel 2: parallel reduce of partials. One block per float4 column-group
// (64 blocks x 256 threads). Thread t sums partial rows t, t+256, ... in
// double; deterministic LDS tree-reduce; threads 0..3 write inv values.
__global__ __launch_bounds__(256) void reduce_inv(
    const float* __restrict__ part, float* __restrict__ inv, int nb) {
    __shared__ double red[4][256];
    const int g = blockIdx.x;    // float4 column group 0..63
    const int t = threadIdx.x;
    const f4* part4 = (const f4*)part;

    double sx = 0.0, sy = 0.0, sz = 0.0, sw = 0.0;
    for (int b = t; b < nb; b += 256) {
        f4 v = part4[(size_t)b * D4 + g];
        sx += (double)v.x; sy += (double)v.y;
        sz += (double)v.z; sw += (double)v.w;
    }
    red[0][t] = sx; red[1][t] = sy; red[2][t] = sz; red[3][t] = sw;
    __syncthreads();
    for (int ofs = 128; ofs > 0; ofs >>= 1) {
        if (t < ofs) {
            red[0][t] += red[0][t + ofs];
            red[1][t] += red[1][t + ofs];
            red[2][t] += red[2][t + ofs];
            red[3][t] += red[3][t + ofs];
        }
        __syncthreads();
    }
    if (t < 4) inv[g * 4 + t] = (float)(1.0 / sqrt(red[t][0]));
}

// Kernel 3: out = x * inv[col]. Same block->chunk mapping as colsq_partial,
// FORWARD order (DRAM-prefetch friendly; round-4 A/B showed no L3 reuse to
// harvest across the dispatch boundary). Cached loads for x; non-temporal
// stores for out (proven win: out doesn't write-allocate / evict).
__global__ __launch_bounds__(256) void scale_cols(
    const f4* __restrict__ x4, const float* __restrict__ inv,
    f4* __restrict__ out4, int rows, int rows_per_block) {
    __shared__ float sinv[D];
    if (threadIdx.x < D) sinv[threadIdx.x] = inv[threadIdx.x];
    __syncthreads();
    const int t  = threadIdx.x;
    const int cg = t & 63;
    const int ro = t >> 6;
    const int r0 = blockIdx.x * rows_per_block;
    const int r1 = min(r0 + rows_per_block, rows);
    const f4 s = ((const f4*)sinv)[cg];

    for (int r = r0 + ro; r < r1; r += 4) {
        const size_t idx = (size_t)r * D4 + cg;
        f4 v = x4[idx];
        __builtin_nontemporal_store(v * s, &out4[idx]);
    }
}

extern "C" void kernel_launch(void* const* d_in, const int* in_sizes, int n_in,
                              void* d_out, int out_size, void* d_ws, size_t ws_size,
                              hipStream_t stream) {
    const float* x = (const float*)d_in[0];
    float* out = (float*)d_out;
    const size_t n = (size_t)in_sizes[0];      // 524288 * 256
    const int rows = (int)(n / D);

    // Adaptive partial-block count so partials + inv fit in d_ws.
    int nb = 2048;
    while (nb > 64 && ((size_t)nb * D + D) * sizeof(float) > ws_size) nb >>= 1;

    float* part = (float*)d_ws;
    float* inv  = part + (size_t)nb * D;

    const int rows_per_block = (rows + nb - 1) / nb;

    colsq_partial<<<nb, 256, 0, stream>>>((const f4*)x, part, rows, rows_per_block);
    reduce_inv<<<D4, 256, 0, stream>>>(part, inv, nb);
    scale_cols<<<nb, 256, 0, stream>>>((const f4*)x, inv, (f4*)out, rows, rows_per_block);
}

// Round 7
// 290.125 us; speedup vs baseline: 2.2907x; 1.0912x over previous
//
#include <hip/hip_runtime.h>

#define D   256   // columns
#define D4  64    // columns as float4

typedef float f4 __attribute__((ext_vector_type(4)));

// Kernel 1: per-block partial column sums of squares, REVERSE row order.
// Block = 256 threads = 64 column-groups (float4) x 4 row-phases.
// Reverse so each chunk's HEAD is the most-recently-read (L3-resident)
// portion when the scale pass starts reading forward.
__global__ __launch_bounds__(256) void colsq_partial(
    const f4* __restrict__ x4, float* __restrict__ part,
    int rows, int rows_per_block) {
    __shared__ f4 red[256];
    const int t  = threadIdx.x;
    const int cg = t & 63;   // which float4 column group
    const int ro = t >> 6;   // row phase 0..3
    const int r0 = blockIdx.x * rows_per_block;
    const int r1 = min(r0 + rows_per_block, rows);

    f4 acc = (f4)0.f;
    const int nq = (r1 - r0 + 3) >> 2;
    for (int k = nq - 1; k >= 0; --k) {
        const int r = r0 + k * 4 + ro;
        if (r < r1) {
            f4 v = x4[(size_t)r * D4 + cg];   // wave reads 1 KiB contiguous
            acc += v * v;
        }
    }
    red[t] = acc;
    __syncthreads();
    if (t < 64) {
        f4 s = red[t] + red[t + 64] + red[t + 128] + red[t + 192];
        ((f4*)part)[(size_t)blockIdx.x * D4 + t] = s;   // deterministic slot
    }
}

// Kernel 2: parallel reduce of partials. One block per float4 column-group
// (64 blocks x 256 threads). Thread t sums partial rows t, t+256, ... in
// double; deterministic LDS tree-reduce; threads 0..3 write inv values.
__global__ __launch_bounds__(256) void reduce_inv(
    const float* __restrict__ part, float* __restrict__ inv, int nb) {
    __shared__ double red[4][256];
    const int g = blockIdx.x;    // float4 column group 0..63
    const int t = threadIdx.x;
    const f4* part4 = (const f4*)part;

    double sx = 0.0, sy = 0.0, sz = 0.0, sw = 0.0;
    for (int b = t; b < nb; b += 256) {
        f4 v = part4[(size_t)b * D4 + g];
        sx += (double)v.x; sy += (double)v.y;
        sz += (double)v.z; sw += (double)v.w;
    }
    red[0][t] = sx; red[1][t] = sy; red[2][t] = sz; red[3][t] = sw;
    __syncthreads();
    for (int ofs = 128; ofs > 0; ofs >>= 1) {
        if (t < ofs) {
            red[0][t] += red[0][t + ofs];
            red[1][t] += red[1][t + ofs];
            red[2][t] += red[2][t + ofs];
            red[3][t] += red[3][t + ofs];
        }
        __syncthreads();
    }
    if (t < 4) inv[g * 4 + t] = (float)(1.0 / sqrt(red[t][0]));
}

// Kernel 3: out = x * inv[col]. Same block->chunk mapping as colsq_partial,
// FORWARD order: the chunk heads (most recently read by the reverse pass 1)
// are L3-resident and get read first; the miss half and the NT write stream
// both run as ascending-address streams (DRAM-prefetch friendly).
__global__ __launch_bounds__(256) void scale_cols(
    const f4* __restrict__ x4, const float* __restrict__ inv,
    f4* __restrict__ out4, int rows, int rows_per_block) {
    __shared__ float sinv[D];
    if (threadIdx.x < D) sinv[threadIdx.x] = inv[threadIdx.x];
    __syncthreads();
    const int t  = threadIdx.x;
    const int cg = t & 63;
    const int ro = t >> 6;
    const int r0 = blockIdx.x * rows_per_block;
    const int r1 = min(r0 + rows_per_block, rows);
    const f4 s = ((const f4*)sinv)[cg];

    for (int r = r0 + ro; r < r1; r += 4) {
        const size_t idx = (size_t)r * D4 + cg;
        f4 v = x4[idx];
        __builtin_nontemporal_store(v * s, &out4[idx]);
    }
}

extern "C" void kernel_launch(void* const* d_in, const int* in_sizes, int n_in,
                              void* d_out, int out_size, void* d_ws, size_t ws_size,
                              hipStream_t stream) {
    const float* x = (const float*)d_in[0];
    float* out = (float*)d_out;
    const size_t n = (size_t)in_sizes[0];      // 524288 * 256
    const int rows = (int)(n / D);

    // Adaptive partial-block count so partials + inv fit in d_ws.
    int nb = 2048;
    while (nb > 64 && ((size_t)nb * D + D) * sizeof(float) > ws_size) nb >>= 1;

    float* part = (float*)d_ws;
    float* inv  = part + (size_t)nb * D;

    const int rows_per_block = (rows + nb - 1) / nb;

    colsq_partial<<<nb, 256, 0, stream>>>((const f4*)x, part, rows, rows_per_block);
    reduce_inv<<<D4, 256, 0, stream>>>(part, inv, nb);
    scale_cols<<<nb, 256, 0, stream>>>((const f4*)x, inv, (f4*)out, rows, rows_per_block);
}